// Round 4
// baseline (74.205 us; speedup 1.0000x reference)
//
#include <hip/hip_runtime.h>

#define BB 4
#define MM 128
#define LL 512
#define DD 768
#define NEGF (-1e30f)

// ISA-controlled load pipeline, v2. Round-3's only delta vs the passing r2
// kernel was 12-byte global_load_lds staging, and it failed numerically ->
// width 12 (unmeasured in the guide; only 4B/16B are HW-verified) is the
// prime suspect. This version keeps the identical pipeline but stages each
// 768B row with 3 width-4 DMA ops (64 lanes x 4B = 256B each). Lane owns
// d-offsets {lane, 64+lane, 128+lane} of its 192-float chunk: identity
// global<->LDS mapping, coalesced loads/stores, 2-way (free) LDS bank alias.
// Ring: 5 rows/wave x 768B; 15 DMA ops in flight; steady-state vmcnt(12)
// (4 newer rows), tail 12/9/6/3/0. In flight per CU: 16 waves x 5 x 768B =
// 60KB -> far above the ~10GB/s/CU demand even at ~1us cold latency.
// Compute: SGPR-ballot uniform branches (bit-exact: h + (-1e30) == -1e30
// for |h| < 7e22, the max-identity given acc init -1e30; all-masked rows
// yield exactly -1e30 in both). Reduction aliases staging LDS post-barrier.

typedef __attribute__((address_space(1))) const unsigned int gu32_t;
typedef __attribute__((address_space(3))) unsigned int lu32_t;

#define WAITVM(N) asm volatile("s_waitcnt vmcnt(" #N ")" ::: "memory")
#define WAITLGKM0() asm volatile("s_waitcnt lgkmcnt(0)" ::: "memory")

__global__ __launch_bounds__(1024, 4) void mention_max_kernel(
    const float* __restrict__ h, const int* __restrict__ mask,
    float* __restrict__ out)
{
    const int lane = threadIdx.x & 63;
    const int wave = threadIdx.x >> 6;   // 0..15
    const int dch  = blockIdx.x;         // 0..3
    const int mch  = blockIdx.y;         // 0..15
    const int b    = blockIdx.z;         // 0..3

    const int m0 = mch * 8;
    const int l0 = wave * 32;

    // 60 KB: staging ring (16 waves x 5 slots x 192 floats); first 48 KB
    // reused as the reduction buffer after the main loop.
    __shared__ float smem[15360];

    // 1) mask loads first (oldest vmcnt slots).
    //    lanes 0..31 -> mention m0+2p, lanes 32..63 -> mention m0+2p+1.
    const int half = lane >> 5;
    const int lrow = lane & 31;
    const int* mp = mask + ((size_t)(b * MM + m0)) * LL + l0 + lrow;
    int mv0 = mp[(0 + half) * LL];
    int mv1 = mp[(2 + half) * LL];
    int mv2 = mp[(4 + half) * LL];
    int mv3 = mp[(6 + half) * LL];

    // Row base (lane term added per-op); wave-uniform LDS slot bases.
    const float* growbase = h + ((size_t)(b * LL + l0)) * DD + dch * 192;
    float* sbase = smem + wave * 960;    // 5 slots x 192 floats

    // One row = 3 width-4 DMA ops; op k covers floats [k*64, k*64+64) of the
    // chunk. LDS dest base wave-uniform; HW writes lane's 4B at base+lane*4.
#define ISSUE(J) do {                                                         \
        __builtin_amdgcn_global_load_lds(                                     \
            (gu32_t*)(growbase + (size_t)(J) * DD + 0 * 64 + lane),           \
            (lu32_t*)(sbase + ((J) % 5) * 192 + 0 * 64), 4, 0, 0);            \
        __builtin_amdgcn_global_load_lds(                                     \
            (gu32_t*)(growbase + (size_t)(J) * DD + 1 * 64 + lane),           \
            (lu32_t*)(sbase + ((J) % 5) * 192 + 1 * 64), 4, 0, 0);            \
        __builtin_amdgcn_global_load_lds(                                     \
            (gu32_t*)(growbase + (size_t)(J) * DD + 2 * 64 + lane),           \
            (lu32_t*)(sbase + ((J) % 5) * 192 + 2 * 64), 4, 0, 0);            \
    } while (0)

    // 2) fill the 5-row pipe (15 DMA ops in flight).
    ISSUE(0); ISSUE(1); ISSUE(2); ISSUE(3); ISSUE(4);

    // 3) ballots -> SGPR masks (compiler waits only on the 4 mask loads).
    unsigned wbits[8];
    { unsigned long long bl = __ballot(mv0 != 0);
      wbits[0] = __builtin_amdgcn_readfirstlane((unsigned)bl);
      wbits[1] = __builtin_amdgcn_readfirstlane((unsigned)(bl >> 32)); }
    { unsigned long long bl = __ballot(mv1 != 0);
      wbits[2] = __builtin_amdgcn_readfirstlane((unsigned)bl);
      wbits[3] = __builtin_amdgcn_readfirstlane((unsigned)(bl >> 32)); }
    { unsigned long long bl = __ballot(mv2 != 0);
      wbits[4] = __builtin_amdgcn_readfirstlane((unsigned)bl);
      wbits[5] = __builtin_amdgcn_readfirstlane((unsigned)(bl >> 32)); }
    { unsigned long long bl = __ballot(mv3 != 0);
      wbits[6] = __builtin_amdgcn_readfirstlane((unsigned)bl);
      wbits[7] = __builtin_amdgcn_readfirstlane((unsigned)(bl >> 32)); }

    float accx[8], accy[8], accz[8];
#pragma unroll
    for (int m = 0; m < 8; ++m) { accx[m] = NEGF; accy[m] = NEGF; accz[m] = NEGF; }

#define CONSUME(I) do {                                                       \
        const float* sp = sbase + ((I) % 5) * 192;                            \
        const float vx = sp[lane];                                            \
        const float vy = sp[64 + lane];                                       \
        const float vz = sp[128 + lane];                                      \
        _Pragma("unroll")                                                     \
        for (int m = 0; m < 8; ++m) {                                         \
            if ((wbits[m] >> (I)) & 1u) {                                     \
                accx[m] = fmaxf(accx[m], vx);                                 \
                accy[m] = fmaxf(accy[m], vy);                                 \
                accz[m] = fmaxf(accz[m], vz);                                 \
            }                                                                 \
        }                                                                     \
    } while (0)

    // 4) steady state: row i's 3 ops retired <=> vmcnt <= 12 (4 newer rows);
    //    lgkmcnt(0) guards the slot's ds_reads before its DMA reuse.
#pragma unroll
    for (int i = 0; i < 27; ++i) {
        WAITVM(12);
        CONSUME(i);
        WAITLGKM0();
        ISSUE(i + 5);
    }
    WAITVM(12); CONSUME(27);
    WAITVM(9);  CONSUME(28);
    WAITVM(6);  CONSUME(29);
    WAITVM(3);  CONSUME(30);
    WAITVM(0);  CONSUME(31);
#undef CONSUME
#undef ISSUE

    // 5) reduction: alias staging LDS (all waves' DMA drained + barrier).
    __syncthreads();
    float (*red)[8][3][64] = (float (*)[8][3][64])smem;
    if (wave >= 8) {
#pragma unroll
        for (int m = 0; m < 8; ++m) {
            red[wave - 8][m][0][lane] = accx[m];
            red[wave - 8][m][1][lane] = accy[m];
            red[wave - 8][m][2][lane] = accz[m];
        }
    }
    __syncthreads();
    if (wave < 8) {
#pragma unroll
        for (int m = 0; m < 8; ++m) {
            red[wave][m][0][lane] = fmaxf(accx[m], red[wave][m][0][lane]);
            red[wave][m][1][lane] = fmaxf(accy[m], red[wave][m][1][lane]);
            red[wave][m][2][lane] = fmaxf(accz[m], red[wave][m][2][lane]);
        }
    }
    __syncthreads();

    // 6) final: 512 threads -> 8 m x 64 lanes; lane ln owns d-offsets
    //    {ln, 64+ln, 128+ln} of the chunk -> perfectly coalesced stores.
    if (threadIdx.x < 512) {
        const int m  = (int)(threadIdx.x >> 6);
        const int ln = (int)(threadIdx.x & 63);
        float vx = red[0][m][0][ln];
        float vy = red[0][m][1][ln];
        float vz = red[0][m][2][ln];
#pragma unroll
        for (int w = 1; w < 8; ++w) {
            vx = fmaxf(vx, red[w][m][0][ln]);
            vy = fmaxf(vy, red[w][m][1][ln]);
            vz = fmaxf(vz, red[w][m][2][ln]);
        }
        float* op = out + ((size_t)(b * MM + m0 + m)) * DD + dch * 192;
        op[ln]       = vx;
        op[64 + ln]  = vy;
        op[128 + ln] = vz;
    }
}

extern "C" void kernel_launch(void* const* d_in, const int* in_sizes, int n_in,
                              void* d_out, int out_size, void* d_ws, size_t ws_size,
                              hipStream_t stream) {
    const float* h    = (const float*)d_in[0];
    const int*   mask = (const int*)d_in[1];
    float*       out  = (float*)d_out;
    dim3 grid(DD / 192, MM / 8, BB);
    mention_max_kernel<<<grid, dim3(1024), 0, stream>>>(h, mask, out);
}

// Round 5
// 69.813 us; speedup vs baseline: 1.0629x; 1.0629x over previous
//
#include <hip/hip_runtime.h>

#define BB 4
#define MM 128
#define LL 512
#define DD 768
#define NEGF (-1e30f)

// Hand-asm register load ring — invisible to the compiler's waitcnt pass.
// r4 post-mortem: LLVM's LDS-DMA tracking is coarse; any ds_read of a
// global_load_lds-written buffer gets a compiler-inserted vmcnt(0) drain,
// collapsing the counted ring to one-row-per-latency (~40us). Fix: issue all
// h loads as volatile inline-asm global_load_dword (compiler emits NO waits
// for asm loads; volatile asm preserves issue order, so vmcnt counts are
// exact). Ring: 12 rows x 3 dwords = 36 outstanding (<63). Steady state
// waits vmcnt(33) (= row done, 11 newer rows in flight). The wait asm ties
// the row's 3 values as "+v" operands: consumes data-depend on the wait,
// the wait data-depends on the loads -> no illegal motion (rule #18).
// Mask loads + ballots complete BEFORE the prefill (sched_barrier fence),
// so the compiler's own vmcnt(0) for them retires with nothing in flight.
// Compute: SGPR-ballot uniform branches (bit-exact: h + (-1e30) == -1e30
// for |h| < 7e22, the max-identity given acc init -1e30; all-masked rows
// yield exactly -1e30 in both). LDS used only for the 16-wave reduction.
__global__ __launch_bounds__(1024, 4) void mention_max_kernel(
    const float* __restrict__ h, const int* __restrict__ mask,
    float* __restrict__ out)
{
    const int lane = threadIdx.x & 63;
    const int wave = threadIdx.x >> 6;   // 0..15
    const int dch  = blockIdx.x;         // 0..3
    const int mch  = blockIdx.y;         // 0..15
    const int b    = blockIdx.z;         // 0..3

    const int m0 = mch * 8;
    const int l0 = wave * 32;

    // 1) mask loads + ballots first; fully retired before the ring starts.
    const int half = lane >> 5;
    const int lrow = lane & 31;
    const int* mp = mask + ((size_t)(b * MM + m0)) * LL + l0 + lrow;
    const int mv0 = mp[(0 + half) * LL];
    const int mv1 = mp[(2 + half) * LL];
    const int mv2 = mp[(4 + half) * LL];
    const int mv3 = mp[(6 + half) * LL];

    unsigned wbits[8];
    { unsigned long long bl = __ballot(mv0 != 0);
      wbits[0] = __builtin_amdgcn_readfirstlane((unsigned)bl);
      wbits[1] = __builtin_amdgcn_readfirstlane((unsigned)(bl >> 32)); }
    { unsigned long long bl = __ballot(mv1 != 0);
      wbits[2] = __builtin_amdgcn_readfirstlane((unsigned)bl);
      wbits[3] = __builtin_amdgcn_readfirstlane((unsigned)(bl >> 32)); }
    { unsigned long long bl = __ballot(mv2 != 0);
      wbits[4] = __builtin_amdgcn_readfirstlane((unsigned)bl);
      wbits[5] = __builtin_amdgcn_readfirstlane((unsigned)(bl >> 32)); }
    { unsigned long long bl = __ballot(mv3 != 0);
      wbits[6] = __builtin_amdgcn_readfirstlane((unsigned)bl);
      wbits[7] = __builtin_amdgcn_readfirstlane((unsigned)(bl >> 32)); }

    // Hard scheduling fence: nothing above may sink into the ring region
    // (keeps the compiler's mask-load vmcnt(0) wait above our prefill).
    __builtin_amdgcn_sched_barrier(0);

    // Per-lane base: lane owns d-offsets {lane, 64+lane, 128+lane} of its
    // 192-float chunk (component strides 256B / 512B = asm offset imms).
    const float* glane = h + ((size_t)(b * LL + l0)) * DD + dch * 192 + lane;

    float sx[12], sy[12], sz[12];          // 12-row ring, constant-indexed

#define ISSUE_ROW(ROW, S) do {                                                \
        const float* _a = glane + (size_t)(ROW) * DD;                         \
        asm volatile("global_load_dword %0, %1, off"                          \
                     : "=v"(sx[S]) : "v"(_a) : "memory");                     \
        asm volatile("global_load_dword %0, %1, off offset:256"               \
                     : "=v"(sy[S]) : "v"(_a) : "memory");                     \
        asm volatile("global_load_dword %0, %1, off offset:512"               \
                     : "=v"(sz[S]) : "v"(_a) : "memory");                     \
    } while (0)

#define WAITROW_(N, S)                                                        \
    asm volatile("s_waitcnt vmcnt(" #N ")"                                    \
                 : "+v"(sx[S]), "+v"(sy[S]), "+v"(sz[S]) :: "memory")
#define WAITROW(N, S) WAITROW_(N, S)

    float accx[8], accy[8], accz[8];
#pragma unroll
    for (int m = 0; m < 8; ++m) { accx[m] = NEGF; accy[m] = NEGF; accz[m] = NEGF; }

#define CONSUME(I, S) do {                                                    \
        const float vx = sx[S], vy = sy[S], vz = sz[S];                       \
        _Pragma("unroll")                                                     \
        for (int m = 0; m < 8; ++m) {                                         \
            if ((wbits[m] >> (I)) & 1u) {                                     \
                accx[m] = fmaxf(accx[m], vx);                                 \
                accy[m] = fmaxf(accy[m], vy);                                 \
                accz[m] = fmaxf(accz[m], vz);                                 \
            }                                                                 \
        }                                                                     \
    } while (0)

    // 2) prefill: rows 0..11 (36 loads outstanding).
    ISSUE_ROW(0, 0);  ISSUE_ROW(1, 1);  ISSUE_ROW(2, 2);  ISSUE_ROW(3, 3);
    ISSUE_ROW(4, 4);  ISSUE_ROW(5, 5);  ISSUE_ROW(6, 6);  ISSUE_ROW(7, 7);
    ISSUE_ROW(8, 8);  ISSUE_ROW(9, 9);  ISSUE_ROW(10, 10); ISSUE_ROW(11, 11);

    // 3) steady state: wait row i (<=33 outstanding), consume, reissue slot.
#define STEP(I, S) do { WAITROW(33, S); CONSUME(I, S); ISSUE_ROW((I) + 12, S); } while (0)
    STEP(0, 0);   STEP(1, 1);   STEP(2, 2);   STEP(3, 3);
    STEP(4, 4);   STEP(5, 5);   STEP(6, 6);   STEP(7, 7);
    STEP(8, 8);   STEP(9, 9);   STEP(10, 10); STEP(11, 11);
    STEP(12, 0);  STEP(13, 1);  STEP(14, 2);  STEP(15, 3);
    STEP(16, 4);  STEP(17, 5);  STEP(18, 6);  STEP(19, 7);
#undef STEP

    // 4) drain rows 20..31 (counts 33,30,...,0).
#define DSTEP(I, S, N) do { WAITROW(N, S); CONSUME(I, S); } while (0)
    DSTEP(20, 8, 33);  DSTEP(21, 9, 30);  DSTEP(22, 10, 27); DSTEP(23, 11, 24);
    DSTEP(24, 0, 21);  DSTEP(25, 1, 18);  DSTEP(26, 2, 15);  DSTEP(27, 3, 12);
    DSTEP(28, 4, 9);   DSTEP(29, 5, 6);   DSTEP(30, 6, 3);   DSTEP(31, 7, 0);
#undef DSTEP
#undef CONSUME
#undef WAITROW
#undef WAITROW_
#undef ISSUE_ROW

    // 5) two-stage 16-wave reduce (48 KB LDS, component-split, conflict-free).
    __shared__ float red[8][8][3][64];
    if (wave >= 8) {
#pragma unroll
        for (int m = 0; m < 8; ++m) {
            red[wave - 8][m][0][lane] = accx[m];
            red[wave - 8][m][1][lane] = accy[m];
            red[wave - 8][m][2][lane] = accz[m];
        }
    }
    __syncthreads();
    if (wave < 8) {
#pragma unroll
        for (int m = 0; m < 8; ++m) {
            red[wave][m][0][lane] = fmaxf(accx[m], red[wave][m][0][lane]);
            red[wave][m][1][lane] = fmaxf(accy[m], red[wave][m][1][lane]);
            red[wave][m][2][lane] = fmaxf(accz[m], red[wave][m][2][lane]);
        }
    }
    __syncthreads();

    // 6) final: 512 threads -> 8 m x 64 lanes; coalesced dword stores.
    if (threadIdx.x < 512) {
        const int m  = (int)(threadIdx.x >> 6);
        const int ln = (int)(threadIdx.x & 63);
        float vx = red[0][m][0][ln];
        float vy = red[0][m][1][ln];
        float vz = red[0][m][2][ln];
#pragma unroll
        for (int w = 1; w < 8; ++w) {
            vx = fmaxf(vx, red[w][m][0][ln]);
            vy = fmaxf(vy, red[w][m][1][ln]);
            vz = fmaxf(vz, red[w][m][2][ln]);
        }
        float* op = out + ((size_t)(b * MM + m0 + m)) * DD + dch * 192;
        op[ln]       = vx;
        op[64 + ln]  = vy;
        op[128 + ln] = vz;
    }
}

extern "C" void kernel_launch(void* const* d_in, const int* in_sizes, int n_in,
                              void* d_out, int out_size, void* d_ws, size_t ws_size,
                              hipStream_t stream) {
    const float* h    = (const float*)d_in[0];
    const int*   mask = (const int*)d_in[1];
    float*       out  = (float*)d_out;
    dim3 grid(DD / 192, MM / 8, BB);
    mention_max_kernel<<<grid, dim3(1024), 0, stream>>>(h, mask, out);
}

// Round 6
// 67.799 us; speedup vs baseline: 1.0945x; 1.0297x over previous
//
#include <hip/hip_runtime.h>

#define BB 4
#define MM 128
#define LL 512
#define DD 768
#define NEGF (-1e30f)

// r5 hand-asm ring + XCD co-location swizzle (single-variable change).
// r5 proved a 36-deep guaranteed load pipe still runs ~40us -> the limiter
// is a per-CU outstanding-miss cap (~56-64 lines by Little's law from r0:
// 409KB/CU / 42.5us at ~400ns latency). With a fixed miss cap, the lever is
// LATENCY per miss: co-locate the 16 mch-blocks that share one (b,dch)
// h-slice on ONE XCD so the slice is HBM-fetched once and the other 15
// blocks hit that XCD's L2 (~200cy vs ~900cy). Dispatch round-robins
// flat%8 across XCDs (T1/m09), so flat = mch*16 + slice puts all 16
// sharers of slice s on XCD s%8 (2 slices x 16 blocks = 32 blocks/XCD,
// 1 block/CU). Ring, ballots, bit-exact compute identical to r5.
__global__ __launch_bounds__(1024, 4) void mention_max_kernel(
    const float* __restrict__ h, const int* __restrict__ mask,
    float* __restrict__ out)
{
    const int lane = threadIdx.x & 63;
    const int wave = threadIdx.x >> 6;   // 0..15

    // XCD co-location decode: flat = mch*16 + slice, slice = b*4 + dch.
    const int flat  = blockIdx.x;        // 0..255
    const int slice = flat & 15;         // -> XCD slice%8
    const int mch   = flat >> 4;         // 0..15
    const int b     = slice >> 2;        // 0..3
    const int dch   = slice & 3;         // 0..3

    const int m0 = mch * 8;
    const int l0 = wave * 32;

    // 1) mask loads + ballots first; fully retired before the ring starts.
    const int half = lane >> 5;
    const int lrow = lane & 31;
    const int* mp = mask + ((size_t)(b * MM + m0)) * LL + l0 + lrow;
    const int mv0 = mp[(0 + half) * LL];
    const int mv1 = mp[(2 + half) * LL];
    const int mv2 = mp[(4 + half) * LL];
    const int mv3 = mp[(6 + half) * LL];

    unsigned wbits[8];
    { unsigned long long bl = __ballot(mv0 != 0);
      wbits[0] = __builtin_amdgcn_readfirstlane((unsigned)bl);
      wbits[1] = __builtin_amdgcn_readfirstlane((unsigned)(bl >> 32)); }
    { unsigned long long bl = __ballot(mv1 != 0);
      wbits[2] = __builtin_amdgcn_readfirstlane((unsigned)bl);
      wbits[3] = __builtin_amdgcn_readfirstlane((unsigned)(bl >> 32)); }
    { unsigned long long bl = __ballot(mv2 != 0);
      wbits[4] = __builtin_amdgcn_readfirstlane((unsigned)bl);
      wbits[5] = __builtin_amdgcn_readfirstlane((unsigned)(bl >> 32)); }
    { unsigned long long bl = __ballot(mv3 != 0);
      wbits[6] = __builtin_amdgcn_readfirstlane((unsigned)bl);
      wbits[7] = __builtin_amdgcn_readfirstlane((unsigned)(bl >> 32)); }

    // Hard scheduling fence: keep the compiler's mask-load waits above the ring.
    __builtin_amdgcn_sched_barrier(0);

    // Per-lane base: lane owns d-offsets {lane, 64+lane, 128+lane} of its
    // 192-float chunk (component strides 256B / 512B = asm offset imms).
    const float* glane = h + ((size_t)(b * LL + l0)) * DD + dch * 192 + lane;

    float sx[12], sy[12], sz[12];          // 12-row ring, constant-indexed

#define ISSUE_ROW(ROW, S) do {                                                \
        const float* _a = glane + (size_t)(ROW) * DD;                         \
        asm volatile("global_load_dword %0, %1, off"                          \
                     : "=v"(sx[S]) : "v"(_a) : "memory");                     \
        asm volatile("global_load_dword %0, %1, off offset:256"               \
                     : "=v"(sy[S]) : "v"(_a) : "memory");                     \
        asm volatile("global_load_dword %0, %1, off offset:512"               \
                     : "=v"(sz[S]) : "v"(_a) : "memory");                     \
    } while (0)

#define WAITROW_(N, S)                                                        \
    asm volatile("s_waitcnt vmcnt(" #N ")"                                    \
                 : "+v"(sx[S]), "+v"(sy[S]), "+v"(sz[S]) :: "memory")
#define WAITROW(N, S) WAITROW_(N, S)

    float accx[8], accy[8], accz[8];
#pragma unroll
    for (int m = 0; m < 8; ++m) { accx[m] = NEGF; accy[m] = NEGF; accz[m] = NEGF; }

#define CONSUME(I, S) do {                                                    \
        const float vx = sx[S], vy = sy[S], vz = sz[S];                       \
        _Pragma("unroll")                                                     \
        for (int m = 0; m < 8; ++m) {                                         \
            if ((wbits[m] >> (I)) & 1u) {                                     \
                accx[m] = fmaxf(accx[m], vx);                                 \
                accy[m] = fmaxf(accy[m], vy);                                 \
                accz[m] = fmaxf(accz[m], vz);                                 \
            }                                                                 \
        }                                                                     \
    } while (0)

    // 2) prefill: rows 0..11 (36 loads outstanding).
    ISSUE_ROW(0, 0);  ISSUE_ROW(1, 1);  ISSUE_ROW(2, 2);  ISSUE_ROW(3, 3);
    ISSUE_ROW(4, 4);  ISSUE_ROW(5, 5);  ISSUE_ROW(6, 6);  ISSUE_ROW(7, 7);
    ISSUE_ROW(8, 8);  ISSUE_ROW(9, 9);  ISSUE_ROW(10, 10); ISSUE_ROW(11, 11);

    // 3) steady state: wait row i (<=33 outstanding), consume, reissue slot.
#define STEP(I, S) do { WAITROW(33, S); CONSUME(I, S); ISSUE_ROW((I) + 12, S); } while (0)
    STEP(0, 0);   STEP(1, 1);   STEP(2, 2);   STEP(3, 3);
    STEP(4, 4);   STEP(5, 5);   STEP(6, 6);   STEP(7, 7);
    STEP(8, 8);   STEP(9, 9);   STEP(10, 10); STEP(11, 11);
    STEP(12, 0);  STEP(13, 1);  STEP(14, 2);  STEP(15, 3);
    STEP(16, 4);  STEP(17, 5);  STEP(18, 6);  STEP(19, 7);
#undef STEP

    // 4) drain rows 20..31 (counts 33,30,...,0).
#define DSTEP(I, S, N) do { WAITROW(N, S); CONSUME(I, S); } while (0)
    DSTEP(20, 8, 33);  DSTEP(21, 9, 30);  DSTEP(22, 10, 27); DSTEP(23, 11, 24);
    DSTEP(24, 0, 21);  DSTEP(25, 1, 18);  DSTEP(26, 2, 15);  DSTEP(27, 3, 12);
    DSTEP(28, 4, 9);   DSTEP(29, 5, 6);   DSTEP(30, 6, 3);   DSTEP(31, 7, 0);
#undef DSTEP
#undef CONSUME
#undef WAITROW
#undef WAITROW_
#undef ISSUE_ROW

    // 5) two-stage 16-wave reduce (48 KB LDS, component-split, conflict-free).
    __shared__ float red[8][8][3][64];
    if (wave >= 8) {
#pragma unroll
        for (int m = 0; m < 8; ++m) {
            red[wave - 8][m][0][lane] = accx[m];
            red[wave - 8][m][1][lane] = accy[m];
            red[wave - 8][m][2][lane] = accz[m];
        }
    }
    __syncthreads();
    if (wave < 8) {
#pragma unroll
        for (int m = 0; m < 8; ++m) {
            red[wave][m][0][lane] = fmaxf(accx[m], red[wave][m][0][lane]);
            red[wave][m][1][lane] = fmaxf(accy[m], red[wave][m][1][lane]);
            red[wave][m][2][lane] = fmaxf(accz[m], red[wave][m][2][lane]);
        }
    }
    __syncthreads();

    // 6) final: 512 threads -> 8 m x 64 lanes; coalesced dword stores.
    if (threadIdx.x < 512) {
        const int m  = (int)(threadIdx.x >> 6);
        const int ln = (int)(threadIdx.x & 63);
        float vx = red[0][m][0][ln];
        float vy = red[0][m][1][ln];
        float vz = red[0][m][2][ln];
#pragma unroll
        for (int w = 1; w < 8; ++w) {
            vx = fmaxf(vx, red[w][m][0][ln]);
            vy = fmaxf(vy, red[w][m][1][ln]);
            vz = fmaxf(vz, red[w][m][2][ln]);
        }
        float* op = out + ((size_t)(b * MM + m0 + m)) * DD + dch * 192;
        op[ln]       = vx;
        op[64 + ln]  = vy;
        op[128 + ln] = vz;
    }
}

extern "C" void kernel_launch(void* const* d_in, const int* in_sizes, int n_in,
                              void* d_out, int out_size, void* d_ws, size_t ws_size,
                              hipStream_t stream) {
    const float* h    = (const float*)d_in[0];
    const int*   mask = (const int*)d_in[1];
    float*       out  = (float*)d_out;
    mention_max_kernel<<<dim3(256), dim3(1024), 0, stream>>>(h, mask, out);
}